// Round 12
// baseline (260.498 us; speedup 1.0000x reference)
//
#include <hip/hip_runtime.h>
#include <hip/hip_bf16.h>

typedef __attribute__((ext_vector_type(8))) short s8v;   // 8 x bf16 bits
typedef __attribute__((ext_vector_type(4))) short s4v;
typedef __attribute__((ext_vector_type(4))) float f4v;

#define B_   8
#define T_   4096
#define C_   1024
#define HS_  64
#define K2_  2048

__device__ __forceinline__ int keep_of(int i) {
    // keep[i] for i in [0,2048): exact integer version of the reference formula
    if (i >= 1024) return 2048 + i;
    int d = 1023 - i;
    return 3071 - ((3 * d * d + 1023) >> 10);
}

__device__ __forceinline__ short bf16_bits(float f) {
    union { __hip_bfloat16 h; short s; } u;
    u.h = __float2bfloat16(f);
    return u.s;
}

// load 8 consecutive fp32, round to bf16, pack into an MFMA bf16 fragment half
__device__ __forceinline__ s8v cvt8f(const float* p) {
    const f4v a = *(const f4v*)p;
    const f4v b = *(const f4v*)(p + 4);
    s8v r;
    r[0] = bf16_bits(a[0]); r[1] = bf16_bits(a[1]);
    r[2] = bf16_bits(a[2]); r[3] = bf16_bits(a[3]);
    r[4] = bf16_bits(b[0]); r[5] = bf16_bits(b[1]);
    r[6] = bf16_bits(b[2]); r[7] = bf16_bits(b[3]);
    return r;
}

// async 16B global -> LDS (direct-to-shared DMA; no VGPR round trip)
__device__ __forceinline__ void gload_lds16(const void* g, void* l) {
    __builtin_amdgcn_global_load_lds(
        (__attribute__((address_space(1))) void*)(g),
        (__attribute__((address_space(3))) void*)(l), 16, 0, 0);
}

// ------------- Kernel W: one-shot fp32 -> bf16 conversion of Wq/Wk/Wv -------
__global__ __launch_bounds__(256) void wcvt_kernel(
    const float* __restrict__ Wq, const float* __restrict__ Wk,
    const float* __restrict__ Wv, short* __restrict__ Wb)
{
    const int idx = (blockIdx.x * 256 + threadIdx.x) * 8;   // 0..196600
    const int mat = idx >> 16;                              // 0,1,2
    const int off = idx & 65535;
    const float* src = (mat == 0) ? Wq : (mat == 1) ? Wk : Wv;
    *(s8v*)(Wb + idx) = cvt8f(src + off);
}

// ---------------- Kernel A: fused QKV projection -----------------------------
// Round 12: single-barrier DOUBLE-BUFFERED staging (T3 minimum 2-phase):
// issue stage(next k-step, other buffer) BEFORE computing current buffer; one
// barrier per step drains loads that had the whole compute phase to land.
// LDS 80KB (x[2][64][64] f32 + W[2][192][64] bf16) -> 2 blocks/CU (160KB).
__global__ __launch_bounds__(256) void qkv_kernel(
    const float* __restrict__ x,
    const short* __restrict__ Wb,   // [192][1024] bf16 (Wq|Wk|Wv rows)
    const float* __restrict__ bq, const float* __restrict__ bk,
    const float* __restrict__ bv,
    __hip_bfloat16* __restrict__ Qo, __hip_bfloat16* __restrict__ Ko,
    __hip_bfloat16* __restrict__ Vt)
{
    __shared__ __align__(16) char smem[81920];
    // xs: [2][64][64] fp32 at 0 (32KB); wsm: [2][192][64] bf16 at 32768 (48KB)

    const int tid  = threadIdx.x;
    const int wave = tid >> 6;
    const int lane = tid & 63;
    const int l16  = lane & 15;
    const int quad = lane >> 4;
    const int row0 = blockIdx.x * 64;

    f4v acc[3][4];                        // [matrix][m-tile]
    #pragma unroll
    for (int m = 0; m < 3; ++m)
        #pragma unroll
        for (int mt = 0; mt < 4; ++mt) {
            acc[m][mt][0] = 0.f; acc[m][mt][1] = 0.f;
            acc[m][mt][2] = 0.f; acc[m][mt][3] = 0.f;
        }

    // staging geometry (lane-contiguous LDS dest; swizzle in global src)
    int xrow[4], xoff[4];
    #pragma unroll
    for (int i = 0; i < 4; ++i) {
        const int f = 256 * i + tid;
        xrow[i] = f >> 4;
        xoff[i] = ((f & 15) ^ (xrow[i] & 7)) * 4;    // floats
    }
    int wrow[6], woff[6];
    #pragma unroll
    for (int i = 0; i < 6; ++i) {
        const int f = 256 * i + tid;
        wrow[i] = f >> 3;
        woff[i] = ((f & 7) ^ (wrow[i] & 7)) * 8;     // shorts
    }

    // prologue: stage k-step 0 into buffer 0
    #pragma unroll
    for (int i = 0; i < 4; ++i)
        gload_lds16(x + (size_t)(row0 + xrow[i]) * C_ + xoff[i],
                    (char*)smem + (256 * i + tid) * 16);
    #pragma unroll
    for (int i = 0; i < 6; ++i)
        gload_lds16(Wb + (size_t)wrow[i] * C_ + woff[i],
                    (char*)smem + 32768 + (256 * i + tid) * 16);
    __syncthreads();

    int buf = 0;
    for (int ks = 0; ks < 16; ++ks) {
        if (ks < 15) {                    // issue next stage into other buffer
            const int k0n = (ks + 1) * 64;
            const int xb = (buf ^ 1) * 16384;
            const int wb2 = (buf ^ 1) * 24576;
            #pragma unroll
            for (int i = 0; i < 4; ++i)
                gload_lds16(x + (size_t)(row0 + xrow[i]) * C_ + k0n + xoff[i],
                            (char*)smem + xb + (256 * i + tid) * 16);
            #pragma unroll
            for (int i = 0; i < 6; ++i)
                gload_lds16(Wb + (size_t)wrow[i] * C_ + k0n + woff[i],
                            (char*)smem + 32768 + wb2 + (256 * i + tid) * 16);
        }

        const float* xsc = (const float*)(smem + buf * 16384);
        const short* wsc = (const short*)(smem + 32768 + buf * 24576);

        #pragma unroll
        for (int kh = 0; kh < 2; ++kh) {
            // A fragments: 4 m-tiles, converted fp32->bf16 once per kh
            s8v a[4];
            #pragma unroll
            for (int mt = 0; mt < 4; ++mt) {
                const int r   = mt * 16 + l16;
                const int ch0 = kh * 8 + quad * 2;
                const float* p0 = xsc + r * 64 + ((ch0    ) ^ (r & 7)) * 4;
                const float* p1 = xsc + r * 64 + ((ch0 + 1) ^ (r & 7)) * 4;
                const f4v u = *(const f4v*)p0;
                const f4v v = *(const f4v*)p1;
                s8v af;
                af[0] = bf16_bits(u[0]); af[1] = bf16_bits(u[1]);
                af[2] = bf16_bits(u[2]); af[3] = bf16_bits(u[3]);
                af[4] = bf16_bits(v[0]); af[5] = bf16_bits(v[1]);
                af[6] = bf16_bits(v[2]); af[7] = bf16_bits(v[3]);
                a[mt] = af;
            }
            // B fragments + MFMA: 3 matrices
            #pragma unroll
            for (int m = 0; m < 3; ++m) {
                const int wr = m * 64 + wave * 16 + l16;     // W row
                const int ch = kh * 4 + quad;                // 16B chunk 0..7
                const s8v bf = *(const s8v*)(wsc + wr * 64 + ((ch ^ (wr & 7)) * 8));
                #pragma unroll
                for (int mt = 0; mt < 4; ++mt)
                    acc[m][mt] = __builtin_amdgcn_mfma_f32_16x16x32_bf16(a[mt], bf, acc[m][mt], 0, 0, 0);
            }
        }
        __syncthreads();                  // drains next-stage + RW sync
        buf ^= 1;
    }

    // epilogue: C/D layout col = lane&15 (folded into wc), row = quad*4+reg
    const int wc = wave * 16 + l16;                  // output column 0..63
    const float bqv = bq[wc], bkv = bk[wc], bvv = bv[wc];
    #pragma unroll
    for (int mt = 0; mt < 4; ++mt) {
        const int rbase = row0 + mt * 16 + quad * 4; // global token row
        #pragma unroll
        for (int r = 0; r < 4; ++r) {
            Qo[(size_t)(rbase + r) * HS_ + wc] = __float2bfloat16(acc[0][mt][r] + bqv);
            Ko[(size_t)(rbase + r) * HS_ + wc] = __float2bfloat16(acc[1][mt][r] + bkv);
        }
        s4v vp;
        #pragma unroll
        for (int r = 0; r < 4; ++r) vp[r] = bf16_bits(acc[2][mt][r] + bvv);
        const int bb = rbase >> 12;                  // batch
        const int t  = rbase & (T_ - 1);             // token within batch
        // tiled V^T: [T/64 tiles][HS][64t], tile = contiguous 8KB
        *(s4v*)(Vt + (size_t)bb * HS_ * T_
                   + (size_t)(t & ~63) * HS_ + wc * 64 + (t & 63)) = vp;
    }
}

// ---------------- Kernel B: flash attention, dbuf LDS staging ---------------
// Round 12: single-barrier double-buffered 128-t steps. Per step: stage
// K[128][64]+V[2][64][64] (32KB) into the other buffer, compute current
// buffer (each wave owns a 32-t chunk: 4 QK MFMA + exp/pack + 4 PV MFMA),
// one barrier. LDS 68KB -> 2 blocks/CU retained (cross-block overlap + dbuf).
__global__ __launch_bounds__(256) void attn_kernel(
    const __hip_bfloat16* __restrict__ Qo,
    const __hip_bfloat16* __restrict__ Ko,
    const __hip_bfloat16* __restrict__ Vt,
    float* __restrict__ out)
{
    __shared__ __align__(16) char smem[69632];
    short* Kb = (short*)smem;                 // [2][128][64] swz, 32KB
    short* Vb = (short*)(smem + 32768);       // [2][2][64][64] swz, 32KB
    float* mL = (float*)smem;                 // epilogue overlay
    float* mO = (float*)(smem + 256);

    const int b    = blockIdx.x & 7;          // XCD-affine batch
    const int pp   = blockIdx.x >> 3;         // 0..63 (0 = heaviest)
    const int tid  = threadIdx.x;
    const int wave = tid >> 6;
    const int lane = tid & 63;
    const int l16  = lane & 15;
    const int quad = lane >> 4;

    short* pw = (short*)(smem + 65536) + wave * 512;   // wave-private P [16][32]

    const short* kb = (const short*)Ko + (size_t)b * T_ * HS_;
    const short* vb = (const short*)Vt + (size_t)b * HS_ * T_;

    // staging geometry (tid-const; global-source swizzle, linear LDS dest)
    int koff[4], voff[4];
    #pragma unroll
    for (int i = 0; i < 4; ++i) {
        const int f = i * 256 + tid;          // 16B chunk index 0..1023
        const int kr = f >> 3;                // K row (t) 0..127
        koff[i] = kr * 64 + (((f & 7) ^ (kr & 7)) * 8);
        const int vt_ = f >> 9;               // V sub-tile 0..1
        const int vd  = (f >> 3) & 63;        // V row (d)
        voff[i] = vt_ * 4096 + vd * 64 + (((f & 7) ^ (vd & 7)) * 8);
    }

    #pragma unroll 1
    for (int which = 0; which < 2; ++which) {
        const int qb = which ? (63 - pp) : (64 + pp);

        // Q fragments (A-operand): m = lane&15, k = quad*8+j ; gather via keep
        const int qt = keep_of(qb * 16 + l16);
        const __hip_bfloat16* qrow = Qo + ((size_t)(b * T_ + qt)) * HS_;
        const s8v aq0 = *(const s8v*)(qrow + quad * 8);
        const s8v aq1 = *(const s8v*)(qrow + 32 + quad * 8);

        int keepr[4];
        #pragma unroll
        for (int r = 0; r < 4; ++r) keepr[r] = keep_of(qb * 16 + quad * 4 + r);

        const int kmin   = keep_of(qb * 16);  // min keep in tile
        const int tmax   = keep_of(qb * 16 + 15);
        const int nt32   = (tmax >> 5) + 1;   // 32-wide t chunks
        const int nsteps = (nt32 + 3) >> 2;   // 128-wide staged steps

        f4v accO[4];
        #pragma unroll
        for (int j = 0; j < 4; ++j) { accO[j][0]=0.f; accO[j][1]=0.f; accO[j][2]=0.f; accO[j][3]=0.f; }
        float l_p[4] = {0.f, 0.f, 0.f, 0.f};

        // prologue: stage step 0 into buffer 0
        #pragma unroll
        for (int i = 0; i < 4; ++i)
            gload_lds16(kb + koff[i], (char*)smem + (i * 256 + tid) * 16);
        #pragma unroll
        for (int i = 0; i < 4; ++i)
            gload_lds16(vb + voff[i], (char*)smem + 32768 + (i * 256 + tid) * 16);
        __syncthreads();

        int buf = 0;
        for (int s = 0; s < nsteps; ++s) {
            if (s + 1 < nsteps) {             // issue next stage (other buffer)
                const int goff = (s + 1) * 8192;      // shorts: 128t*64 / 2*4096
                const int ldsb = (buf ^ 1) * 16384;   // bytes
                #pragma unroll
                for (int i = 0; i < 4; ++i)
                    gload_lds16(kb + goff + koff[i],
                                (char*)smem + ldsb + (i * 256 + tid) * 16);
                #pragma unroll
                for (int i = 0; i < 4; ++i)
                    gload_lds16(vb + goff + voff[i],
                                (char*)smem + 32768 + ldsb + (i * 256 + tid) * 16);
            }

            const int c = s * 4 + wave;       // this wave's 32-t chunk
            if (c < nt32) {
                const int t0 = c << 5;
                const short* Kc = Kb + buf * 8192;
                const short* Vc = Vb + buf * 8192 + (wave >> 1) * 4096;
                const int tch = (wave & 1) * 4;       // t-chunk base in V rows

                // ---- S = Q K^T (swizzled ds_read_b128) ----
                f4v s2[2];
                #pragma unroll
                for (int jn = 0; jn < 2; ++jn) {
                    const int row = wave * 32 + jn * 16 + l16;
                    const s8v bk0 = *(const s8v*)(Kc + row * 64 + (((quad    ) ^ (row & 7)) * 8));
                    const s8v bk1 = *(const s8v*)(Kc + row * 64 + (((quad + 4) ^ (row & 7)) * 8));
                    f4v z; z[0]=0.f; z[1]=0.f; z[2]=0.f; z[3]=0.f;
                    z = __builtin_amdgcn_mfma_f32_16x16x32_bf16(aq0, bk0, z, 0, 0, 0);
                    z = __builtin_amdgcn_mfma_f32_16x16x32_bf16(aq1, bk1, z, 0, 0, 0);
                    s2[jn] = z;
                }

                // p = valid ? exp(s/32) : 0 ; mask only on boundary chunks
                if (t0 + 31 <= kmin) {        // fully valid (common)
                    #pragma unroll
                    for (int jn = 0; jn < 2; ++jn) {
                        const int t = jn * 16 + l16;
                        const int chunk = t >> 3;
                        #pragma unroll
                        for (int r = 0; r < 4; ++r) {
                            const float p = __expf(s2[jn][r] * 0.03125f);
                            l_p[r] += p;
                            const int m = quad * 4 + r;
                            pw[m * 32 + ((chunk ^ (m & 3)) * 8) + (t & 7)] = bf16_bits(p);
                        }
                    }
                } else {                      // boundary chunk
                    #pragma unroll
                    for (int jn = 0; jn < 2; ++jn) {
                        const int t = jn * 16 + l16;
                        const int valid_t = t0 + t;
                        const int chunk = t >> 3;
                        #pragma unroll
                        for (int r = 0; r < 4; ++r) {
                            const float e = __expf(s2[jn][r] * 0.03125f);
                            const float p = (valid_t <= keepr[r]) ? e : 0.0f;
                            l_p[r] += p;
                            const int m = quad * 4 + r;
                            pw[m * 32 + ((chunk ^ (m & 3)) * 8) + (t & 7)] = bf16_bits(p);
                        }
                    }
                }
                const s8v ap = *(const s8v*)(pw + l16 * 32 + ((quad ^ (l16 & 3)) * 8));

                // ---- O += P V (k=32; swizzled ds_read_b128) ----
                #pragma unroll
                for (int jd = 0; jd < 4; ++jd) {
                    const int rd = jd * 16 + l16;
                    const s8v bv = *(const s8v*)(Vc + rd * 64 + (((tch + quad) ^ (rd & 7)) * 8));
                    accO[jd] = __builtin_amdgcn_mfma_f32_16x16x32_bf16(ap, bv, accO[jd], 0, 0, 0);
                }
            }
            __syncthreads();                  // drains next-stage + RW sync
            buf ^= 1;
        }

        // ---- one deferred l butterfly (16 lanes hold cols of each row) ----
        #pragma unroll
        for (int off = 1; off < 16; off <<= 1)
            #pragma unroll
            for (int r = 0; r < 4; ++r) l_p[r] += __shfl_xor(l_p[r], off);

        // ---- cross-wave merge -> normalize -> direct output ----
        __syncthreads();                      // K/V/P LDS now dead
        #pragma unroll
        for (int r = 0; r < 4; ++r) {
            const int row = quad * 4 + r;
            if (l16 == 0) mL[wave * 16 + row] = l_p[r];
            #pragma unroll
            for (int jd = 0; jd < 4; ++jd)
                mO[wave * 1024 + row * 64 + jd * 16 + l16] = accO[jd][r];
        }
        __syncthreads();

        {
            const int row = tid >> 4;         // 0..15
            const int col = (tid & 15) * 4;   // 0..60
            float L = 0.f;
            #pragma unroll
            for (int w = 0; w < 4; ++w) L += mL[w * 16 + row];
            const float inv = 1.0f / L;
            f4v o; o[0]=0.f; o[1]=0.f; o[2]=0.f; o[3]=0.f;
            #pragma unroll
            for (int w = 0; w < 4; ++w) {
                const f4v ow = *(const f4v*)(mO + w * 1024 + row * 64 + col);
                #pragma unroll
                for (int j = 0; j < 4; ++j) o[j] += ow[j];
            }
            #pragma unroll
            for (int j = 0; j < 4; ++j) o[j] *= inv;
            *(f4v*)(out + ((size_t)(b * K2_ + qb * 16 + row)) * HS_ + col) = o;
        }
        __syncthreads();                      // mO dead before next qb staging
    }
}

extern "C" void kernel_launch(void* const* d_in, const int* in_sizes, int n_in,
                              void* d_out, int out_size, void* d_ws, size_t ws_size,
                              hipStream_t stream) {
    (void)in_sizes; (void)n_in; (void)out_size; (void)ws_size;
    const float* x  = (const float*)d_in[0];
    const float* Wq = (const float*)d_in[1];
    const float* bq = (const float*)d_in[2];
    const float* Wk = (const float*)d_in[3];
    const float* bk = (const float*)d_in[4];
    const float* Wv = (const float*)d_in[5];
    const float* bv = (const float*)d_in[6];

    __hip_bfloat16* Qo = (__hip_bfloat16*)d_ws;                       // 4 MB
    __hip_bfloat16* Ko = Qo + (size_t)B_ * T_ * HS_;                  // 4 MB
    __hip_bfloat16* Vt = Ko + (size_t)B_ * T_ * HS_;                  // 4 MB (tiled)
    short*          Wb = (short*)(Vt + (size_t)B_ * HS_ * T_);        // 384 KB
    float* o = (float*)d_out;

    wcvt_kernel<<<dim3(96), dim3(256), 0, stream>>>(Wq, Wk, Wv, Wb);
    qkv_kernel<<<dim3((B_ * T_) / 64), dim3(256), 0, stream>>>(
        x, Wb, bq, bk, bv, Qo, Ko, Vt);
    attn_kernel<<<dim3(512), dim3(256), 0, stream>>>(Qo, Ko, Vt, o);
}